// Round 9
// baseline (112.909 us; speedup 1.0000x reference)
//
#include <hip/hip_runtime.h>

// ConvAutoEncoder: B=16384, T=64, C=2, D=4
// out = [encoder_out (B*128 f32) | decoded (B*128 f32)]
// Fused kernel: 256 threads / 4 waves / 8 batches per block, 2048 blocks (8/CU).
// MFMA tiles are 16 cols wide; cols 8..15 are don't-care (row-remapped reads, guarded stores).

typedef __attribute__((ext_vector_type(8))) short bf16x8;
typedef __attribute__((ext_vector_type(4))) float f32x4;

__device__ __forceinline__ unsigned short f2bf(float f) {
    unsigned int u = __builtin_bit_cast(unsigned int, f);
    return (unsigned short)((u + 0x7FFFu + ((u >> 16) & 1u)) >> 16);
}
__device__ __forceinline__ unsigned int pack2bf(float a, float b) {
    return (unsigned int)f2bf(a) | ((unsigned int)f2bf(b) << 16);
}

#define SWZ(row) (((row) & 7) << 3)   // ushort-index XOR == byte XOR ((row&7)<<4)

// ---------------- kernel 0: weight prep ----------------
__global__ void k0_prep(const float* __restrict__ w1, const float* __restrict__ w2,
                        const float* __restrict__ cw, const float* __restrict__ cb,
                        unsigned short* __restrict__ w1b, unsigned short* __restrict__ w2b,
                        unsigned short* __restrict__ wcv, float* __restrict__ biasf) {
    int i = blockIdx.x * 256 + threadIdx.x;      // 0..65535
    if (i < 512 * 128) { w1b[i] = f2bf(w1[i]); w2b[i] = f2bf(w2[i]); }
    if (i < 128 * 256) {
        int f = i >> 8, kd = i & 255;            // f = 2*o + s, kd = node*4 + d
        int o = f >> 1, s = f & 1, node = kd >> 2, d = kd & 3;
        int k = d - s;
        float v = (k >= 0 && k < 3) ? cw[o * 192 + node * 3 + k] : 0.f;
        wcv[i] = f2bf(v);
    }
    if (i < 128) biasf[i] = cb[i >> 1];
}

// ---------------- fused kernel ----------------
// 4 waves, 8 batches/block. Attention: wave wv rows 2wv..2wv+1, 2 interleaved streams.
// Conv: fb={wv,wv+4}. L1: nb=8wv..8wv+7. L2: mb={wv,wv+4}. Swizzled LDS between phases.
__global__ __launch_bounds__(256, 4) void k_fused(
    const float* __restrict__ x,             // (B,64,2)
    const float* __restrict__ W_gat,         // (4,2)
    const float* __restrict__ a_attn,        // (8,)
    const unsigned short* __restrict__ w1b,  // (512,128)
    const unsigned short* __restrict__ w2b,  // (128,512)
    const unsigned short* __restrict__ wcv,  // (128,256)
    const float* __restrict__ biasf,         // (128,)
    const float* __restrict__ b1,            // (512,)
    const float* __restrict__ b2,            // (128,)
    float* __restrict__ enc_out,             // (B,128) f32
    float* __restrict__ dec_out)             // (B,128) f32
{
    __shared__ __align__(16) unsigned char smem[14336];
    unsigned short* h_lds    = (unsigned short*)smem;            // [8][256] bf16 swz, 4KB
    unsigned short* flat_lds = (unsigned short*)(smem + 4096);   // [8][128] bf16 swz, 2KB
    float*          scr      = (float*)(smem + 6144);            // [4 waves][2 rows][4][64], 8KB } aliased
    unsigned short* hdec_lds = (unsigned short*)(smem + 6144);   // [8][512] bf16 swz, 8KB       }

    const int tid = threadIdx.x, lane = tid & 63, wv = tid >> 6;  // wv 0..3
    const int r = lane & 15, g = lane >> 4;
    const int rr = r & 7;                  // row-remap for don't-care cols 8..15
    const int base = blockIdx.x * 8;

    // ================= attention (2 rows per wave, 2 interleaved streams) =============
    {
        const float Wg00 = W_gat[0], Wg01 = W_gat[1], Wg10 = W_gat[2], Wg11 = W_gat[3];
        const float Wg20 = W_gat[4], Wg21 = W_gat[5], Wg30 = W_gat[6], Wg31 = W_gat[7];
        const float as0 = a_attn[0], as1 = a_attn[1], as2 = a_attn[2], as3 = a_attn[3];
        const float ad0 = a_attn[4], ad1 = a_attn[5], ad2 = a_attn[6], ad3 = a_attn[7];
        // es = x0*cs0 + x1*cs1 ; ed = x0*cd0 + x1*cd1  (exact fold of z@a)
        const float cs0 = as0 * Wg00 + as1 * Wg10 + as2 * Wg20 + as3 * Wg30;
        const float cs1 = as0 * Wg01 + as1 * Wg11 + as2 * Wg21 + as3 * Wg31;
        const float cd0 = ad0 * Wg00 + ad1 * Wg10 + ad2 * Wg20 + ad3 * Wg30;
        const float cd1 = ad0 * Wg01 + ad1 * Wg11 + ad2 * Wg21 + ad3 * Wg31;
        const float L2E = 1.4426950408889634f;
        const float SL = 0.2f;

        float* wbuf = scr + wv * 512;        // 2 rows x 256 floats (x0|x1|u|v)
        float x0s[2], x1s[2], us[2], vs[2], Us[2], Vs[2];

        #pragma unroll
        for (int t = 0; t < 2; ++t) {
            const float2 xv = ((const float2*)x)[(size_t)(base + wv * 2 + t) * 64 + lane];
            const float x0 = xv.x, x1 = xv.y;
            const float es = x0 * cs0 + x1 * cs1;
            const float ed = x0 * cd0 + x1 * cd1;
            const float u = __builtin_amdgcn_exp2f(es * L2E);         // e^{es}
            const float v = __builtin_amdgcn_exp2f(es * (SL * L2E));  // e^{0.2 es}
            const float U = __builtin_amdgcn_exp2f(ed * L2E);
            const float V = __builtin_amdgcn_exp2f(ed * (SL * L2E));
            float* Bf = wbuf + t * 256;
            Bf[lane] = x0; Bf[64 + lane] = x1; Bf[128 + lane] = u; Bf[192 + lane] = v;
            x0s[t] = x0; x1s[t] = x1; us[t] = u; vs[t] = v; Us[t] = U; Vs[t] = V;
        }

        {
            const float* Ba = wbuf;
            const float* Bb = wbuf + 256;
            const f32x4 Ua4 = {Us[0], Us[0], Us[0], Us[0]};
            const f32x4 Va4 = {Vs[0], Vs[0], Vs[0], Vs[0]};
            const f32x4 Ub4 = {Us[1], Us[1], Us[1], Us[1]};
            const f32x4 Vb4 = {Vs[1], Vs[1], Vs[1], Vs[1]};
            f32x4 Sa = {0.f, 0.f, 0.f, 0.f}, A0a = Sa, A1a = Sa;
            f32x4 Sb = Sa, A0b = Sa, A1b = Sa;
            #pragma unroll
            for (int i4 = 0; i4 < 16; ++i4) {
                const f32x4 ax0 = *(const f32x4*)(Ba + i4 * 4);
                const f32x4 ax1 = *(const f32x4*)(Ba + 64 + i4 * 4);
                const f32x4 au  = *(const f32x4*)(Ba + 128 + i4 * 4);
                const f32x4 av  = *(const f32x4*)(Ba + 192 + i4 * 4);
                const f32x4 bx0 = *(const f32x4*)(Bb + i4 * 4);
                const f32x4 bx1 = *(const f32x4*)(Bb + 64 + i4 * 4);
                const f32x4 bu  = *(const f32x4*)(Bb + 128 + i4 * 4);
                const f32x4 bv  = *(const f32x4*)(Bb + 192 + i4 * 4);
                const f32x4 Pa = __builtin_elementwise_max(au * Ua4, av * Va4);
                const f32x4 Pb = __builtin_elementwise_max(bu * Ub4, bv * Vb4);
                Sa += Pa; A0a += Pa * ax0; A1a += Pa * ax1;
                Sb += Pb; A0b += Pb * bx0; A1b += Pb * bx1;
            }
            #pragma unroll
            for (int t = 0; t < 2; ++t) {
                const f32x4 S4  = t ? Sb : Sa;
                const f32x4 A04 = t ? A0b : A0a;
                const f32x4 A14 = t ? A1b : A1a;
                const float pS = fmaxf(us[t] * Us[t], vs[t] * Vs[t]);   // self term, exact
                const float S  = (S4[0] + S4[1]) + (S4[2] + S4[3]) - pS;
                const float A0 = (A04[0] + A04[1]) + (A04[2] + A04[3]) - pS * x0s[t];
                const float A1 = (A14[0] + A14[1]) + (A14[2] + A14[3]) - pS * x1s[t];
                const float rs = 1.0f / S;
                const float h0 = (Wg00 * A0 + Wg01 * A1) * rs;
                const float h1 = (Wg10 * A0 + Wg11 * A1) * rs;
                const float h2 = (Wg20 * A0 + Wg21 * A1) * rs;
                const float h3 = (Wg30 * A0 + Wg31 * A1) * rs;
                const int lr = wv * 2 + t;                              // 0..7
                const int hidx = (lr * 256 + lane * 4) ^ SWZ(lr);
                *(uint2*)(&h_lds[hidx]) = make_uint2(pack2bf(h0, h1), pack2bf(h2, h3));
            }
        }
    }
    __syncthreads();

    // ================= conv (as matmul, K=256): fb = wv, wv+4 =================
    f32x4 accc[2];
    accc[0] = (f32x4){0.f, 0.f, 0.f, 0.f};
    accc[1] = (f32x4){0.f, 0.f, 0.f, 0.f};
    #pragma unroll
    for (int kc = 0; kc < 8; ++kc) {
        const bf16x8 hf  = *(const bf16x8*)(&h_lds[(rr * 256 + kc * 32 + g * 8) ^ SWZ(rr)]);
        const bf16x8 wfa = *(const bf16x8*)(wcv + (wv * 16 + r) * 256 + kc * 32 + g * 8);
        const bf16x8 wfb = *(const bf16x8*)(wcv + ((wv + 4) * 16 + r) * 256 + kc * 32 + g * 8);
        accc[0] = __builtin_amdgcn_mfma_f32_16x16x32_bf16(wfa, hf, accc[0], 0, 0, 0);
        accc[1] = __builtin_amdgcn_mfma_f32_16x16x32_bf16(wfb, hf, accc[1], 0, 0, 0);
    }
    if (r < 8) {
        #pragma unroll
        for (int q = 0; q < 2; ++q) {
            const int f0 = (wv + q * 4) * 16 + g * 4;
            const float4 bs = *(const float4*)(biasf + f0);
            const float v0 = accc[q][0] + bs.x, v1 = accc[q][1] + bs.y;
            const float v2 = accc[q][2] + bs.z, v3 = accc[q][3] + bs.w;
            *(float4*)(enc_out + (size_t)(base + r) * 128 + f0) = make_float4(v0, v1, v2, v3);
            const int fidx = (r * 128 + f0) ^ SWZ(r);
            *(uint2*)(&flat_lds[fidx]) = make_uint2(pack2bf(v0, v1), pack2bf(v2, v3));
        }
    }
    __syncthreads();

    // ================= decoder layer1: 128 -> 512, relu; nb = 8wv..8wv+7 =================
    bf16x8 ff1[4];
    #pragma unroll
    for (int kb = 0; kb < 4; ++kb)
        ff1[kb] = *(const bf16x8*)(&flat_lds[(rr * 128 + kb * 32 + g * 8) ^ SWZ(rr)]);
    #pragma unroll
    for (int t = 0; t < 8; ++t) {
        const int nb = wv * 8 + t;
        f32x4 a1 = (f32x4){0.f, 0.f, 0.f, 0.f};
        #pragma unroll
        for (int kb = 0; kb < 4; ++kb) {
            const bf16x8 wf = *(const bf16x8*)(w1b + (nb * 16 + r) * 128 + kb * 32 + g * 8);
            a1 = __builtin_amdgcn_mfma_f32_16x16x32_bf16(wf, ff1[kb], a1, 0, 0, 0);
        }
        if (r < 8) {
            const int n0 = nb * 16 + g * 4;
            const float4 bs = *(const float4*)(b1 + n0);
            const float v0 = fmaxf(a1[0] + bs.x, 0.f);
            const float v1 = fmaxf(a1[1] + bs.y, 0.f);
            const float v2 = fmaxf(a1[2] + bs.z, 0.f);
            const float v3 = fmaxf(a1[3] + bs.w, 0.f);
            const int hdidx = (r * 512 + n0) ^ SWZ(r);
            *(uint2*)(&hdec_lds[hdidx]) = make_uint2(pack2bf(v0, v1), pack2bf(v2, v3));
        }
    }
    __syncthreads();

    // ================= decoder layer2: 512 -> 128; mb = wv, wv+4 =================
    f32x4 acc2[2];
    acc2[0] = (f32x4){0.f, 0.f, 0.f, 0.f};
    acc2[1] = (f32x4){0.f, 0.f, 0.f, 0.f};
    #pragma unroll
    for (int np = 0; np < 16; ++np) {
        const bf16x8 hfd = *(const bf16x8*)(&hdec_lds[(rr * 512 + np * 32 + g * 8) ^ SWZ(rr)]);
        const bf16x8 wfa = *(const bf16x8*)(w2b + (wv * 16 + r) * 512 + np * 32 + g * 8);
        const bf16x8 wfb = *(const bf16x8*)(w2b + ((wv + 4) * 16 + r) * 512 + np * 32 + g * 8);
        acc2[0] = __builtin_amdgcn_mfma_f32_16x16x32_bf16(wfa, hfd, acc2[0], 0, 0, 0);
        acc2[1] = __builtin_amdgcn_mfma_f32_16x16x32_bf16(wfb, hfd, acc2[1], 0, 0, 0);
    }
    if (r < 8) {
        #pragma unroll
        for (int q = 0; q < 2; ++q) {
            const int m0 = (wv + q * 4) * 16 + g * 4;
            const float4 bs = *(const float4*)(b2 + m0);
            *(float4*)(dec_out + (size_t)(base + r) * 128 + m0) =
                make_float4(acc2[q][0] + bs.x, acc2[q][1] + bs.y,
                            acc2[q][2] + bs.z, acc2[q][3] + bs.w);
        }
    }
}

extern "C" void kernel_launch(void* const* d_in, const int* in_sizes, int n_in,
                              void* d_out, int out_size, void* d_ws, size_t ws_size,
                              hipStream_t stream) {
    const float* x      = (const float*)d_in[0];
    const float* W_gat  = (const float*)d_in[1];
    const float* a_attn = (const float*)d_in[2];
    const float* conv_w = (const float*)d_in[3];
    const float* conv_b = (const float*)d_in[4];
    const float* dec_w1 = (const float*)d_in[5];
    const float* dec_b1 = (const float*)d_in[6];
    const float* dec_w2 = (const float*)d_in[7];
    const float* dec_b2 = (const float*)d_in[8];
    float* out = (float*)d_out;

    const int B = in_sizes[0] / 128;                 // 16384
    unsigned short* w1b = (unsigned short*)d_ws;     // 512*128
    unsigned short* w2b = w1b + 512 * 128;           // 128*512
    unsigned short* wcv = w2b + 128 * 512;           // 128*256
    float* biasf = (float*)(wcv + 128 * 256);        // 128

    k0_prep<<<256, 256, 0, stream>>>(dec_w1, dec_w2, conv_w, conv_b, w1b, w2b, wcv, biasf);

    k_fused<<<B / 8, 256, 0, stream>>>(x, W_gat, a_attn, w1b, w2b, wcv, biasf,
                                       dec_b1, dec_b2, out, out + (size_t)B * 128);
}

// Round 10
// 55.263 us; speedup vs baseline: 2.0431x; 2.0431x over previous
//
#include <hip/hip_runtime.h>

// ConvAutoEncoder: B=16384, T=64, C=2, D=4
// out = [encoder_out (B*128 f32) | decoded (B*128 f32)]
// k_attn: folded attention -> h bf16 (stored in dec-out region, dead before dec writes)
// k_convdec: conv + decoder, 8 waves / 32 batches / block, per-phase VGPR weight preload.

typedef __attribute__((ext_vector_type(8))) short bf16x8;
typedef __attribute__((ext_vector_type(4))) float f32x4;

__device__ __forceinline__ unsigned short f2bf(float f) {
    unsigned int u = __builtin_bit_cast(unsigned int, f);
    return (unsigned short)((u + 0x7FFFu + ((u >> 16) & 1u)) >> 16);
}
__device__ __forceinline__ unsigned int pack2bf(float a, float b) {
    return (unsigned int)f2bf(a) | ((unsigned int)f2bf(b) << 16);
}

#define SWZ(row) (((row) & 7) << 3)   // ushort-index XOR == byte XOR ((row&7)<<4)

// ---------------- kernel 0: weight prep ----------------
__global__ void k0_prep(const float* __restrict__ w1, const float* __restrict__ w2,
                        const float* __restrict__ cw, const float* __restrict__ cb,
                        unsigned short* __restrict__ w1b, unsigned short* __restrict__ w2b,
                        unsigned short* __restrict__ wcv, float* __restrict__ biasf) {
    int i = blockIdx.x * 256 + threadIdx.x;      // 0..65535
    if (i < 512 * 128) { w1b[i] = f2bf(w1[i]); w2b[i] = f2bf(w2[i]); }
    if (i < 128 * 256) {
        int f = i >> 8, kd = i & 255;            // f = 2*o + s, kd = node*4 + d
        int o = f >> 1, s = f & 1, node = kd >> 2, d = kd & 3;
        int k = d - s;
        float v = (k >= 0 && k < 3) ? cw[o * 192 + node * 3 + k] : 0.f;
        wcv[i] = f2bf(v);
    }
    if (i < 128) biasf[i] = cb[i >> 1];
}

// ---------------- k_attn: GAT attention -> h bf16 ----------------
// 2048 blocks x 4 waves; wave handles rows base+2wv, base+2wv+1 (2 interleaved streams).
__global__ __launch_bounds__(256, 4) void k_attn(
    const float* __restrict__ x,       // (B,64,2)
    const float* __restrict__ W_gat,   // (4,2)
    const float* __restrict__ a_attn,  // (8,)
    uint2* __restrict__ h_out)         // (B,64) -> 4 bf16 per node
{
    __shared__ float scr[4 * 512];     // per wave: 2 rows x 256 floats (x0|x1|u|v), 8KB

    const int tid = threadIdx.x, lane = tid & 63, wv = tid >> 6;  // wv 0..3
    const int base = blockIdx.x * 8;

    const float Wg00 = W_gat[0], Wg01 = W_gat[1], Wg10 = W_gat[2], Wg11 = W_gat[3];
    const float Wg20 = W_gat[4], Wg21 = W_gat[5], Wg30 = W_gat[6], Wg31 = W_gat[7];
    const float as0 = a_attn[0], as1 = a_attn[1], as2 = a_attn[2], as3 = a_attn[3];
    const float ad0 = a_attn[4], ad1 = a_attn[5], ad2 = a_attn[6], ad3 = a_attn[7];
    // es = x0*cs0 + x1*cs1 ; ed = x0*cd0 + x1*cd1  (exact fold of z@a)
    const float cs0 = as0 * Wg00 + as1 * Wg10 + as2 * Wg20 + as3 * Wg30;
    const float cs1 = as0 * Wg01 + as1 * Wg11 + as2 * Wg21 + as3 * Wg31;
    const float cd0 = ad0 * Wg00 + ad1 * Wg10 + ad2 * Wg20 + ad3 * Wg30;
    const float cd1 = ad0 * Wg01 + ad1 * Wg11 + ad2 * Wg21 + ad3 * Wg31;
    const float L2E = 1.4426950408889634f;
    const float SL = 0.2f;

    float* wbuf = scr + wv * 512;
    float x0s[2], x1s[2], us[2], vs[2], Us[2], Vs[2];

    #pragma unroll
    for (int t = 0; t < 2; ++t) {
        const float2 xv = ((const float2*)x)[(size_t)(base + wv * 2 + t) * 64 + lane];
        const float x0 = xv.x, x1 = xv.y;
        const float es = x0 * cs0 + x1 * cs1;
        const float ed = x0 * cd0 + x1 * cd1;
        const float u = __builtin_amdgcn_exp2f(es * L2E);         // e^{es}
        const float v = __builtin_amdgcn_exp2f(es * (SL * L2E));  // e^{0.2 es}
        const float U = __builtin_amdgcn_exp2f(ed * L2E);
        const float V = __builtin_amdgcn_exp2f(ed * (SL * L2E));
        float* Bf = wbuf + t * 256;
        Bf[lane] = x0; Bf[64 + lane] = x1; Bf[128 + lane] = u; Bf[192 + lane] = v;
        x0s[t] = x0; x1s[t] = x1; us[t] = u; vs[t] = v; Us[t] = U; Vs[t] = V;
    }

    const float* Ba = wbuf;
    const float* Bb = wbuf + 256;
    const f32x4 Ua4 = {Us[0], Us[0], Us[0], Us[0]};
    const f32x4 Va4 = {Vs[0], Vs[0], Vs[0], Vs[0]};
    const f32x4 Ub4 = {Us[1], Us[1], Us[1], Us[1]};
    const f32x4 Vb4 = {Vs[1], Vs[1], Vs[1], Vs[1]};
    f32x4 Sa = {0.f, 0.f, 0.f, 0.f}, A0a = Sa, A1a = Sa;
    f32x4 Sb = Sa, A0b = Sa, A1b = Sa;
    #pragma unroll
    for (int i4 = 0; i4 < 16; ++i4) {
        const f32x4 ax0 = *(const f32x4*)(Ba + i4 * 4);
        const f32x4 ax1 = *(const f32x4*)(Ba + 64 + i4 * 4);
        const f32x4 au  = *(const f32x4*)(Ba + 128 + i4 * 4);
        const f32x4 av  = *(const f32x4*)(Ba + 192 + i4 * 4);
        const f32x4 bx0 = *(const f32x4*)(Bb + i4 * 4);
        const f32x4 bx1 = *(const f32x4*)(Bb + 64 + i4 * 4);
        const f32x4 bu  = *(const f32x4*)(Bb + 128 + i4 * 4);
        const f32x4 bv  = *(const f32x4*)(Bb + 192 + i4 * 4);
        const f32x4 Pa = __builtin_elementwise_max(au * Ua4, av * Va4);
        const f32x4 Pb = __builtin_elementwise_max(bu * Ub4, bv * Vb4);
        Sa += Pa; A0a += Pa * ax0; A1a += Pa * ax1;
        Sb += Pb; A0b += Pb * bx0; A1b += Pb * bx1;
    }
    #pragma unroll
    for (int t = 0; t < 2; ++t) {
        const f32x4 S4  = t ? Sb : Sa;
        const f32x4 A04 = t ? A0b : A0a;
        const f32x4 A14 = t ? A1b : A1a;
        const float pS = fmaxf(us[t] * Us[t], vs[t] * Vs[t]);   // self term, exact
        const float S  = (S4[0] + S4[1]) + (S4[2] + S4[3]) - pS;
        const float A0 = (A04[0] + A04[1]) + (A04[2] + A04[3]) - pS * x0s[t];
        const float A1 = (A14[0] + A14[1]) + (A14[2] + A14[3]) - pS * x1s[t];
        const float rs = 1.0f / S;
        const float h0 = (Wg00 * A0 + Wg01 * A1) * rs;
        const float h1 = (Wg10 * A0 + Wg11 * A1) * rs;
        const float h2 = (Wg20 * A0 + Wg21 * A1) * rs;
        const float h3 = (Wg30 * A0 + Wg31 * A1) * rs;
        h_out[(size_t)(base + wv * 2 + t) * 64 + lane] =
            make_uint2(pack2bf(h0, h1), pack2bf(h2, h3));
    }
}

// ---------------- k_convdec: conv + decoder, weight slices preloaded in VGPRs -------
// 512 blocks x 8 waves, 32 batches (2 tiles of 16). Conv: fb=wv. L1: nb=4wv..4wv+3.
// L2: mb=wv. Weights loaded once per block per phase; tiles looped inside each phase.
__global__ __launch_bounds__(512, 2) void k_convdec(
    const unsigned short* h_bf,              // (B,256) bf16 (aliases dec_out)
    const unsigned short* __restrict__ w1b,  // (512,128)
    const unsigned short* __restrict__ w2b,  // (128,512)
    const unsigned short* __restrict__ wcv,  // (128,256)
    const float* __restrict__ biasf,         // (128,)
    const float* __restrict__ b1,            // (512,)
    const float* __restrict__ b2,            // (128,)
    float* __restrict__ enc_out,             // (B,128) f32
    float* dec_out)                          // (B,128) f32 (aliases h_bf)
{
    __shared__ unsigned short flat_lds[2][16 * 128];   // 8KB swz
    __shared__ unsigned short hdec_lds[2][16 * 512];   // 32KB swz

    const int tid = threadIdx.x, lane = tid & 63, wv = tid >> 6;   // wv 0..7
    const int r = lane & 15, g = lane >> 4;
    const int base = blockIdx.x * 32;

    // ======== conv (as matmul K=256): wave owns fb=wv; weights preloaded (8 frags) ====
    bf16x8 cw[8];
    #pragma unroll
    for (int kc = 0; kc < 8; ++kc)
        cw[kc] = *(const bf16x8*)(wcv + (wv * 16 + r) * 256 + kc * 32 + g * 8);
    const float4 bsf = *(const float4*)(biasf + wv * 16 + g * 4);
    #pragma unroll
    for (int t2 = 0; t2 < 2; ++t2) {
        const int row = base + t2 * 16 + r;
        f32x4 aca = (f32x4){0.f, 0.f, 0.f, 0.f};
        f32x4 acb = (f32x4){0.f, 0.f, 0.f, 0.f};
        #pragma unroll
        for (int kc = 0; kc < 4; ++kc) {
            const bf16x8 hf0 = *(const bf16x8*)(h_bf + (size_t)row * 256 + kc * 32 + g * 8);
            const bf16x8 hf1 = *(const bf16x8*)(h_bf + (size_t)row * 256 + (kc + 4) * 32 + g * 8);
            aca = __builtin_amdgcn_mfma_f32_16x16x32_bf16(cw[kc], hf0, aca, 0, 0, 0);
            acb = __builtin_amdgcn_mfma_f32_16x16x32_bf16(cw[kc + 4], hf1, acb, 0, 0, 0);
        }
        const f32x4 cc = aca + acb;
        const int f0 = wv * 16 + g * 4;
        const float v0 = cc[0] + bsf.x, v1 = cc[1] + bsf.y;
        const float v2 = cc[2] + bsf.z, v3 = cc[3] + bsf.w;
        *(float4*)(enc_out + (size_t)row * 128 + f0) = make_float4(v0, v1, v2, v3);
        const int fidx = (r * 128 + f0) ^ SWZ(r);
        *(uint2*)(&flat_lds[t2][fidx]) = make_uint2(pack2bf(v0, v1), pack2bf(v2, v3));
    }
    __syncthreads();

    // ======== decoder layer1: 128->512 relu; nb=4wv..4wv+3; weights preloaded (16) ====
    bf16x8 w1r[4][4];
    #pragma unroll
    for (int t = 0; t < 4; ++t)
        #pragma unroll
        for (int kb = 0; kb < 4; ++kb)
            w1r[t][kb] = *(const bf16x8*)(w1b + ((wv * 4 + t) * 16 + r) * 128 + kb * 32 + g * 8);
    #pragma unroll
    for (int t2 = 0; t2 < 2; ++t2) {
        bf16x8 ff[4];
        #pragma unroll
        for (int kb = 0; kb < 4; ++kb)
            ff[kb] = *(const bf16x8*)(&flat_lds[t2][(r * 128 + kb * 32 + g * 8) ^ SWZ(r)]);
        #pragma unroll
        for (int t = 0; t < 4; ++t) {
            f32x4 a1 = (f32x4){0.f, 0.f, 0.f, 0.f};
            #pragma unroll
            for (int kb = 0; kb < 4; ++kb)
                a1 = __builtin_amdgcn_mfma_f32_16x16x32_bf16(w1r[t][kb], ff[kb], a1, 0, 0, 0);
            const int n0 = (wv * 4 + t) * 16 + g * 4;
            const float4 bs = *(const float4*)(b1 + n0);
            const float v0 = fmaxf(a1[0] + bs.x, 0.f);
            const float v1 = fmaxf(a1[1] + bs.y, 0.f);
            const float v2 = fmaxf(a1[2] + bs.z, 0.f);
            const float v3 = fmaxf(a1[3] + bs.w, 0.f);
            const int hdidx = (r * 512 + n0) ^ SWZ(r);
            *(uint2*)(&hdec_lds[t2][hdidx]) = make_uint2(pack2bf(v0, v1), pack2bf(v2, v3));
        }
    }
    __syncthreads();

    // ======== decoder layer2: 512->128; mb=wv; weights preloaded (16 frags) ==========
    bf16x8 w2r[16];
    #pragma unroll
    for (int np = 0; np < 16; ++np)
        w2r[np] = *(const bf16x8*)(w2b + (wv * 16 + r) * 512 + np * 32 + g * 8);
    const float4 bs2 = *(const float4*)(b2 + wv * 16 + g * 4);
    #pragma unroll
    for (int t2 = 0; t2 < 2; ++t2) {
        f32x4 d2a = (f32x4){0.f, 0.f, 0.f, 0.f};
        f32x4 d2b = (f32x4){0.f, 0.f, 0.f, 0.f};
        #pragma unroll
        for (int np = 0; np < 8; ++np) {
            const bf16x8 h0 = *(const bf16x8*)(&hdec_lds[t2][(r * 512 + np * 32 + g * 8) ^ SWZ(r)]);
            const bf16x8 h1 = *(const bf16x8*)(&hdec_lds[t2][(r * 512 + (np + 8) * 32 + g * 8) ^ SWZ(r)]);
            d2a = __builtin_amdgcn_mfma_f32_16x16x32_bf16(w2r[np], h0, d2a, 0, 0, 0);
            d2b = __builtin_amdgcn_mfma_f32_16x16x32_bf16(w2r[np + 8], h1, d2b, 0, 0, 0);
        }
        const f32x4 dd = d2a + d2b;
        const int m0 = wv * 16 + g * 4;
        *(float4*)(dec_out + (size_t)(base + t2 * 16 + r) * 128 + m0) =
            make_float4(dd[0] + bs2.x, dd[1] + bs2.y, dd[2] + bs2.z, dd[3] + bs2.w);
    }
}

extern "C" void kernel_launch(void* const* d_in, const int* in_sizes, int n_in,
                              void* d_out, int out_size, void* d_ws, size_t ws_size,
                              hipStream_t stream) {
    const float* x      = (const float*)d_in[0];
    const float* W_gat  = (const float*)d_in[1];
    const float* a_attn = (const float*)d_in[2];
    const float* conv_w = (const float*)d_in[3];
    const float* conv_b = (const float*)d_in[4];
    const float* dec_w1 = (const float*)d_in[5];
    const float* dec_b1 = (const float*)d_in[6];
    const float* dec_w2 = (const float*)d_in[7];
    const float* dec_b2 = (const float*)d_in[8];
    float* out = (float*)d_out;

    const int B = in_sizes[0] / 128;                 // 16384
    unsigned short* w1b = (unsigned short*)d_ws;     // 512*128
    unsigned short* w2b = w1b + 512 * 128;           // 128*512
    unsigned short* wcv = w2b + 128 * 512;           // 128*256
    float* biasf = (float*)(wcv + 128 * 256);        // 128

    // h bf16 lives in the decoded-output region (read fully by conv before dec writes)
    unsigned short* h_bf = (unsigned short*)(out + (size_t)B * 128);

    k0_prep<<<256, 256, 0, stream>>>(dec_w1, dec_w2, conv_w, conv_b, w1b, w2b, wcv, biasf);

    k_attn<<<B / 8, 256, 0, stream>>>(x, W_gat, a_attn, (uint2*)h_bf);

    k_convdec<<<B / 32, 512, 0, stream>>>(h_bf, w1b, w2b, wcv, biasf, dec_b1, dec_b2,
                                          out, out + (size_t)B * 128);
}